// Round 1
// baseline (428.634 us; speedup 1.0000x reference)
//
#include <hip/hip_runtime.h>
#include <math.h>

#define BB 32
#define MM 2048
#define KK 4
#define EE 128
#define GG 128
#define VV 50000
#define HOPS 3

// ---------------- GRU cell: one block per batch row ----------------
__global__ __launch_bounds__(384) void gru_kernel(
    const float* __restrict__ emb0,   // emb table 0 [V][E]
    const int*   __restrict__ y,      // [B]
    const float* __restrict__ hprev,  // [B][G]
    const float* __restrict__ W_ih,   // [3G][E]
    const float* __restrict__ W_hh,   // [3G][G]
    const float* __restrict__ b_ih,   // [3G]
    const float* __restrict__ b_hh,   // [3G]
    float* __restrict__ h_out,        // d_out [B][G]
    float* __restrict__ q)            // ws    [B][G]
{
    int b = blockIdx.x;
    int t = threadIdx.x;
    __shared__ float x[EE], h[GG], gi[3*GG], gh[3*GG];
    if (t < EE)            x[t]       = emb0[(size_t)y[b]*EE + t];
    else if (t < 2*EE)     h[t-EE]    = hprev[b*GG + (t-EE)];
    __syncthreads();
    {
        float accI = b_ih[t], accH = b_hh[t];
        const float* wi = W_ih + (size_t)t*EE;
        const float* wh = W_hh + (size_t)t*GG;
        #pragma unroll 8
        for (int e = 0; e < EE; e++) { accI += x[e]*wi[e]; accH += h[e]*wh[e]; }
        gi[t] = accI; gh[t] = accH;
    }
    __syncthreads();
    if (t < GG) {
        float r = 1.f/(1.f + __expf(-(gi[t]        + gh[t])));
        float z = 1.f/(1.f + __expf(-(gi[GG+t]     + gh[GG+t])));
        float n = tanhf(gi[2*GG+t] + r*gh[2*GG+t]);
        float hn = (1.f - z)*n + z*h[t];
        h_out[b*GG + t] = hn;
        q[b*GG + t]     = hn;
    }
}

// ---------------- attention scores: one wave per memory slot ----------------
__global__ __launch_bounds__(256) void scores_kernel(
    const float* __restrict__ embT,   // emb + hop*V*E
    const int*   __restrict__ ctx,    // [B][M][K]
    const float* __restrict__ q,      // [B][E]
    float* __restrict__ p)            // [B][M]
{
    int gid  = blockIdx.x * 4 + (threadIdx.x >> 6);  // == b*M + m
    int lane = threadIdx.x & 63;
    int b    = gid >> 11;                            // /M (M=2048)
    const int4 c = *(const int4*)(ctx + (size_t)gid*KK);
    float2 qv = *(const float2*)(q + b*EE + lane*2);
    float2 v0 = *(const float2*)(embT + (size_t)c.x*EE + lane*2);
    float2 v1 = *(const float2*)(embT + (size_t)c.y*EE + lane*2);
    float2 v2 = *(const float2*)(embT + (size_t)c.z*EE + lane*2);
    float2 v3 = *(const float2*)(embT + (size_t)c.w*EE + lane*2);
    float sx = v0.x + v1.x + v2.x + v3.x;
    float sy = v0.y + v1.y + v2.y + v3.y;
    float acc = sx*qv.x + sy*qv.y;
    #pragma unroll
    for (int off = 32; off; off >>= 1) acc += __shfl_down(acc, off);
    if (lane == 0) p[gid] = acc;
}

// ---------------- softmax over M: one block per batch row ----------------
__global__ __launch_bounds__(256) void softmax_m_kernel(
    const float* __restrict__ p,      // [B][M]
    float* __restrict__ attn)         // [B][M]
{
    int b = blockIdx.x, t = threadIdx.x;
    const float* row = p + (size_t)b*MM;
    float v[8];
    float mx = -INFINITY;
    #pragma unroll
    for (int i = 0; i < 8; i++) { v[i] = row[t + i*256]; mx = fmaxf(mx, v[i]); }
    __shared__ float red[6];
    int w = t >> 6, lane = t & 63;
    #pragma unroll
    for (int off = 32; off; off >>= 1) mx = fmaxf(mx, __shfl_down(mx, off));
    if (lane == 0) red[w] = mx;
    __syncthreads();
    if (t == 0) { float m2 = fmaxf(fmaxf(red[0],red[1]), fmaxf(red[2],red[3])); red[4] = m2; }
    __syncthreads();
    mx = red[4];
    float sum = 0.f;
    #pragma unroll
    for (int i = 0; i < 8; i++) { v[i] = __expf(v[i] - mx); sum += v[i]; }
    #pragma unroll
    for (int off = 32; off; off >>= 1) sum += __shfl_down(sum, off);
    if (lane == 0) red[w] = sum;
    __syncthreads();
    if (t == 0) { red[5] = 1.f / (red[0]+red[1]+red[2]+red[3]); }
    __syncthreads();
    float rs = red[5];
    #pragma unroll
    for (int i = 0; i < 8; i++) attn[(size_t)b*MM + t + i*256] = v[i]*rs;
}

// ---------------- weighted memory read: partial sums over slot chunks ----------------
__global__ __launch_bounds__(256) void oacc_kernel(
    const float* __restrict__ embT,   // emb + (hop+1)*V*E
    const int*   __restrict__ ctx,    // [B][M][K]
    const float* __restrict__ attn,   // [B][M]
    float* __restrict__ o_part)       // [32][B][E]
{
    int blk = blockIdx.x;             // b*32 + s
    int b = blk >> 5, s = blk & 31;
    int w = threadIdx.x >> 6, lane = threadIdx.x & 63;
    int m0 = s*64 + w*16;
    float ax = 0.f, ay = 0.f;
    for (int i = 0; i < 16; i++) {
        int m = m0 + i;
        float a = attn[(size_t)b*MM + m];
        const int4 c = *(const int4*)(ctx + (size_t)(b*MM + m)*KK);
        float2 v0 = *(const float2*)(embT + (size_t)c.x*EE + lane*2);
        float2 v1 = *(const float2*)(embT + (size_t)c.y*EE + lane*2);
        float2 v2 = *(const float2*)(embT + (size_t)c.z*EE + lane*2);
        float2 v3 = *(const float2*)(embT + (size_t)c.w*EE + lane*2);
        ax += a * (v0.x + v1.x + v2.x + v3.x);
        ay += a * (v0.y + v1.y + v2.y + v3.y);
    }
    __shared__ float red[4][EE];
    red[w][lane*2]   = ax;
    red[w][lane*2+1] = ay;
    __syncthreads();
    if (threadIdx.x < EE) {
        int e = threadIdx.x;
        float v = red[0][e] + red[1][e] + red[2][e] + red[3][e];
        o_part[((size_t)s*BB + b)*EE + e] = v;
    }
}

// ---------------- q update (and o1 save) ----------------
__global__ __launch_bounds__(256) void qupd_kernel(
    const float* __restrict__ o_part, // [32][B][E]
    float* __restrict__ q,            // [B][E]
    float* __restrict__ o1,
    int save_o1)
{
    int i = blockIdx.x*256 + threadIdx.x;   // over B*E = 4096
    float v = 0.f;
    #pragma unroll 8
    for (int s = 0; s < 32; s++) v += o_part[(size_t)s*BB*EE + i];
    q[i] += v;
    if (save_o1) o1[i] = v;
}

// ---------------- vocab logits: 32x50000x256 GEMM, LDS tiled ----------------
__global__ __launch_bounds__(256) void logits_kernel(
    const float* __restrict__ h,      // [B][G] (from d_out)
    const float* __restrict__ o1,     // [B][E] (ws)
    const float* __restrict__ Wv,     // [V][256]
    const float* __restrict__ bv,     // [V]
    float* __restrict__ logits)       // [B][V] (d_out p_vocab region)
{
    __shared__ float U[BB][256];      // 32 KB
    __shared__ float Wl[256][33];     // ~33 KB, padded stride 33 -> conflict-free reads
    int t = threadIdx.x;
    for (int i = t; i < BB*256; i += 256) {
        int b = i >> 8, e = i & 255;
        U[b][e] = (e < GG) ? h[b*GG + e] : o1[b*EE + (e - GG)];
    }
    int v0 = blockIdx.x * 256;
    int v  = v0 + t;
    float acc[BB];
    #pragma unroll
    for (int b = 0; b < BB; b++) acc[b] = 0.f;
    __syncthreads();
    for (int ec = 0; ec < 256; ec += 32) {
        // cooperative load of W tile [256 v][32 e]
        #pragma unroll
        for (int j = 0; j < 8; j++) {
            int f   = t + j*256;          // float4 index in [0,2048)
            int row = f >> 3;
            int c4  = (f & 7) * 4;
            int vv  = v0 + row;
            float4 val = make_float4(0.f,0.f,0.f,0.f);
            if (vv < VV) val = *(const float4*)(Wv + (size_t)vv*256 + ec + c4);
            Wl[row][c4+0] = val.x; Wl[row][c4+1] = val.y;
            Wl[row][c4+2] = val.z; Wl[row][c4+3] = val.w;
        }
        __syncthreads();
        #pragma unroll
        for (int e = 0; e < 32; e++) {
            float wv = Wl[t][e];
            #pragma unroll
            for (int b = 0; b < BB; b++) acc[b] += wv * U[b][ec + e];
        }
        __syncthreads();
    }
    if (v < VV) {
        float bb = bv[v];
        #pragma unroll
        for (int b = 0; b < BB; b++) logits[(size_t)b*VV + v] = acc[b] + bb;
    }
}

// ---------------- vocab softmax stats: one block per batch row ----------------
__global__ __launch_bounds__(1024) void vstats_kernel(
    const float* __restrict__ logits, // [B][V]
    float* __restrict__ stats)        // [B][2] = {max, 1/sum}
{
    int b = blockIdx.x, t = threadIdx.x;
    const float* row = logits + (size_t)b*VV;
    __shared__ float red[16];
    __shared__ float bmax, bsum;
    int w = t >> 6, lane = t & 63;
    float mx = -INFINITY;
    for (int i = t; i < VV; i += 1024) mx = fmaxf(mx, row[i]);
    #pragma unroll
    for (int off = 32; off; off >>= 1) mx = fmaxf(mx, __shfl_down(mx, off));
    if (lane == 0) red[w] = mx;
    __syncthreads();
    if (t == 0) { float m2 = red[0]; for (int i = 1; i < 16; i++) m2 = fmaxf(m2, red[i]); bmax = m2; }
    __syncthreads();
    float m = bmax;
    float sum = 0.f;
    for (int i = t; i < VV; i += 1024) sum += __expf(row[i] - m);
    #pragma unroll
    for (int off = 32; off; off >>= 1) sum += __shfl_down(sum, off);
    if (lane == 0) red[w] = sum;
    __syncthreads();
    if (t == 0) {
        float s = 0.f; for (int i = 0; i < 16; i++) s += red[i];
        bsum = s;
        stats[b*2]   = m;
        stats[b*2+1] = 1.f / s;
    }
}

// ---------------- finalize p_vocab in place ----------------
__global__ __launch_bounds__(256) void vfinal_kernel(
    float* __restrict__ logits,       // [B][V], in-place
    const float* __restrict__ stats)
{
    int i = blockIdx.x*256 + threadIdx.x;
    if (i >= BB*VV) return;
    int b = i / VV;
    logits[i] = __expf(logits[i] - stats[b*2]) * stats[b*2+1];
}

extern "C" void kernel_launch(void* const* d_in, const int* in_sizes, int n_in,
                              void* d_out, int out_size, void* d_ws, size_t ws_size,
                              hipStream_t stream) {
    const int*   ctx    = (const int*)  d_in[0];
    const float* h_prev = (const float*)d_in[1];
    const int*   y      = (const int*)  d_in[2];
    const float* emb    = (const float*)d_in[3];
    const float* W_ih   = (const float*)d_in[4];
    const float* W_hh   = (const float*)d_in[5];
    const float* b_ih   = (const float*)d_in[6];
    const float* b_hh   = (const float*)d_in[7];
    const float* Wv     = (const float*)d_in[8];
    const float* bv     = (const float*)d_in[9];

    float* out_h    = (float*)d_out;                 // [B][G]
    float* out_pv   = out_h + BB*GG;                 // [B][V]
    float* out_attn = out_pv + (size_t)BB*VV;        // [B][M]

    float* ws     = (float*)d_ws;
    float* q      = ws;                    // 4096
    float* o1     = q + BB*EE;             // 4096
    float* o_part = o1 + BB*EE;            // 32*32*128 = 131072
    float* p      = o_part + 32*BB*EE;     // 65536
    float* attn   = p + BB*MM;             // 65536
    float* stats  = attn + BB*MM;          // 64

    gru_kernel<<<BB, 384, 0, stream>>>(emb, y, h_prev, W_ih, W_hh, b_ih, b_hh, out_h, q);

    for (int hop = 0; hop < HOPS; hop++) {
        const float* embA = emb + (size_t)hop*VV*EE;
        const float* embC = emb + (size_t)(hop+1)*VV*EE;
        scores_kernel<<<(BB*MM)/4, 256, 0, stream>>>(embA, ctx, q, p);
        float* attn_dst = (hop == HOPS-1) ? out_attn : attn;
        softmax_m_kernel<<<BB, 256, 0, stream>>>(p, attn_dst);
        oacc_kernel<<<BB*32, 256, 0, stream>>>(embC, ctx, attn_dst, o_part);
        qupd_kernel<<<(BB*EE)/256, 256, 0, stream>>>(o_part, q, o1, hop == 0 ? 1 : 0);
    }

    logits_kernel<<<(VV + 255)/256, 256, 0, stream>>>(out_h, o1, Wv, bv, out_pv);
    vstats_kernel<<<BB, 1024, 0, stream>>>(out_pv, stats);
    vfinal_kernel<<<(BB*VV + 255)/256, 256, 0, stream>>>(out_pv, stats);
}

// Round 2
// 360.521 us; speedup vs baseline: 1.1889x; 1.1889x over previous
//
#include <hip/hip_runtime.h>
#include <math.h>

#define BB 32
#define MM 2048
#define KK 4
#define EE 128
#define GG 128
#define VV 50000
#define HOPS 3

// ---------------- GRU cell: one block per batch row ----------------
__global__ __launch_bounds__(384) void gru_kernel(
    const float* __restrict__ emb0,   // emb table 0 [V][E]
    const int*   __restrict__ y,      // [B]
    const float* __restrict__ hprev,  // [B][G]
    const float* __restrict__ W_ih,   // [3G][E]
    const float* __restrict__ W_hh,   // [3G][G]
    const float* __restrict__ b_ih,   // [3G]
    const float* __restrict__ b_hh,   // [3G]
    float* __restrict__ h_out,        // d_out [B][G]
    float* __restrict__ q)            // ws    [B][G]
{
    int b = blockIdx.x;
    int t = threadIdx.x;
    __shared__ float x[EE], h[GG], gi[3*GG], gh[3*GG];
    if (t < EE)            x[t]       = emb0[(size_t)y[b]*EE + t];
    else if (t < 2*EE)     h[t-EE]    = hprev[b*GG + (t-EE)];
    __syncthreads();
    {
        float accI = b_ih[t], accH = b_hh[t];
        const float* wi = W_ih + (size_t)t*EE;
        const float* wh = W_hh + (size_t)t*GG;
        #pragma unroll 8
        for (int e = 0; e < EE; e++) { accI += x[e]*wi[e]; accH += h[e]*wh[e]; }
        gi[t] = accI; gh[t] = accH;
    }
    __syncthreads();
    if (t < GG) {
        float r = 1.f/(1.f + __expf(-(gi[t]        + gh[t])));
        float z = 1.f/(1.f + __expf(-(gi[GG+t]     + gh[GG+t])));
        float n = tanhf(gi[2*GG+t] + r*gh[2*GG+t]);
        float hn = (1.f - z)*n + z*h[t];
        h_out[b*GG + t] = hn;
        q[b*GG + t]     = hn;
    }
}

// ---------------- attention scores: one wave per memory slot ----------------
__global__ __launch_bounds__(256) void scores_kernel(
    const float* __restrict__ embT,   // emb + hop*V*E
    const int*   __restrict__ ctx,    // [B][M][K]
    const float* __restrict__ q,      // [B][E]
    float* __restrict__ p)            // [B][M]
{
    int gid  = blockIdx.x * 4 + (threadIdx.x >> 6);  // == b*M + m
    int lane = threadIdx.x & 63;
    int b    = gid >> 11;                            // /M (M=2048)
    const int4 c = *(const int4*)(ctx + (size_t)gid*KK);
    float2 qv = *(const float2*)(q + b*EE + lane*2);
    float2 v0 = *(const float2*)(embT + (size_t)c.x*EE + lane*2);
    float2 v1 = *(const float2*)(embT + (size_t)c.y*EE + lane*2);
    float2 v2 = *(const float2*)(embT + (size_t)c.z*EE + lane*2);
    float2 v3 = *(const float2*)(embT + (size_t)c.w*EE + lane*2);
    float sx = v0.x + v1.x + v2.x + v3.x;
    float sy = v0.y + v1.y + v2.y + v3.y;
    float acc = sx*qv.x + sy*qv.y;
    #pragma unroll
    for (int off = 32; off; off >>= 1) acc += __shfl_down(acc, off);
    if (lane == 0) p[gid] = acc;
}

// ---------------- softmax over M: one block per batch row ----------------
__global__ __launch_bounds__(256) void softmax_m_kernel(
    const float* __restrict__ p,      // [B][M]
    float* __restrict__ attn)         // [B][M]
{
    int b = blockIdx.x, t = threadIdx.x;
    const float* row = p + (size_t)b*MM;
    float v[8];
    float mx = -INFINITY;
    #pragma unroll
    for (int i = 0; i < 8; i++) { v[i] = row[t + i*256]; mx = fmaxf(mx, v[i]); }
    __shared__ float red[6];
    int w = t >> 6, lane = t & 63;
    #pragma unroll
    for (int off = 32; off; off >>= 1) mx = fmaxf(mx, __shfl_down(mx, off));
    if (lane == 0) red[w] = mx;
    __syncthreads();
    if (t == 0) { float m2 = fmaxf(fmaxf(red[0],red[1]), fmaxf(red[2],red[3])); red[4] = m2; }
    __syncthreads();
    mx = red[4];
    float sum = 0.f;
    #pragma unroll
    for (int i = 0; i < 8; i++) { v[i] = __expf(v[i] - mx); sum += v[i]; }
    #pragma unroll
    for (int off = 32; off; off >>= 1) sum += __shfl_down(sum, off);
    if (lane == 0) red[w] = sum;
    __syncthreads();
    if (t == 0) { red[5] = 1.f / (red[0]+red[1]+red[2]+red[3]); }
    __syncthreads();
    float rs = red[5];
    #pragma unroll
    for (int i = 0; i < 8; i++) attn[(size_t)b*MM + t + i*256] = v[i]*rs;
}

// ---------------- weighted memory read: partial sums over slot chunks ----------------
__global__ __launch_bounds__(256) void oacc_kernel(
    const float* __restrict__ embT,   // emb + (hop+1)*V*E
    const int*   __restrict__ ctx,    // [B][M][K]
    const float* __restrict__ attn,   // [B][M]
    float* __restrict__ o_part)       // [32][B][E]
{
    int blk = blockIdx.x;             // b*32 + s
    int b = blk >> 5, s = blk & 31;
    int w = threadIdx.x >> 6, lane = threadIdx.x & 63;
    int m0 = s*64 + w*16;
    float ax = 0.f, ay = 0.f;
    for (int i = 0; i < 16; i++) {
        int m = m0 + i;
        float a = attn[(size_t)b*MM + m];
        const int4 c = *(const int4*)(ctx + (size_t)(b*MM + m)*KK);
        float2 v0 = *(const float2*)(embT + (size_t)c.x*EE + lane*2);
        float2 v1 = *(const float2*)(embT + (size_t)c.y*EE + lane*2);
        float2 v2 = *(const float2*)(embT + (size_t)c.z*EE + lane*2);
        float2 v3 = *(const float2*)(embT + (size_t)c.w*EE + lane*2);
        ax += a * (v0.x + v1.x + v2.x + v3.x);
        ay += a * (v0.y + v1.y + v2.y + v3.y);
    }
    __shared__ float red[4][EE];
    red[w][lane*2]   = ax;
    red[w][lane*2+1] = ay;
    __syncthreads();
    if (threadIdx.x < EE) {
        int e = threadIdx.x;
        float v = red[0][e] + red[1][e] + red[2][e] + red[3][e];
        o_part[((size_t)s*BB + b)*EE + e] = v;
    }
}

// ---------------- q update (and o1 save) ----------------
__global__ __launch_bounds__(256) void qupd_kernel(
    const float* __restrict__ o_part, // [32][B][E]
    float* __restrict__ q,            // [B][E]
    float* __restrict__ o1,
    int save_o1)
{
    int i = blockIdx.x*256 + threadIdx.x;   // over B*E = 4096
    float v = 0.f;
    #pragma unroll 8
    for (int s = 0; s < 32; s++) v += o_part[(size_t)s*BB*EE + i];
    q[i] += v;
    if (save_o1) o1[i] = v;
}

// ---------------- vocab logits: 50000x32x256 GEMM, 4v x 4b register tile ----------------
// block = 256 threads, v-tile = 128 rows. LDS: Ut[256][32] (32 KB) + Wt[32][132] (16.9 KB)
// -> 49 KB -> 3 blocks/CU. Grid = 391 blocks. Inner step: 2x ds_read_b128 per 16 FMA.
__global__ __launch_bounds__(256) void logits_kernel(
    const float* __restrict__ h,      // [B][G] (from d_out)
    const float* __restrict__ o1,     // [B][E] (ws)
    const float* __restrict__ Wv,     // [V][256]
    const float* __restrict__ bv,     // [V]
    float* __restrict__ logits)       // [B][V] (d_out p_vocab region)
{
    __shared__ float Ut[256][32];     // [e][b]
    __shared__ float Wt[32][132];     // [e_local][v_local], pad 128->132
    int t = threadIdx.x;
    // stage U = concat(h, o1) transposed to [e][b]
    for (int i = t; i < 256*32; i += 256) {
        int e = i >> 5, b = i & 31;
        Ut[e][b] = (e < GG) ? h[b*GG + e] : o1[b*EE + (e - GG)];
    }
    int vg = t & 31;        // 32 v-groups of 4
    int bg = t >> 5;        // 8 b-groups of 4
    int v0 = blockIdx.x * 128;
    float acc[4][4];
    #pragma unroll
    for (int i = 0; i < 4; i++)
        #pragma unroll
        for (int j = 0; j < 4; j++) acc[i][j] = 0.f;

    int vrow = t >> 1;          // 0..127
    int half = t & 1;           // which 16-float half of the row
    const float* wrow = Wv + (size_t)(v0 + vrow)*256 + half*16;
    bool vok = (v0 + vrow) < VV;

    for (int ec = 0; ec < 256; ec += 32) {
        __syncthreads();        // protect Wt from previous iteration's readers
        // load W tile [128 v][32 e], store transposed into Wt[e][v]
        #pragma unroll
        for (int j = 0; j < 4; j++) {
            float4 w = make_float4(0.f, 0.f, 0.f, 0.f);
            if (vok) w = *(const float4*)(wrow + ec + j*4);
            int e0 = half*16 + j*4;
            Wt[e0+0][vrow] = w.x;
            Wt[e0+1][vrow] = w.y;
            Wt[e0+2][vrow] = w.z;
            Wt[e0+3][vrow] = w.w;
        }
        __syncthreads();
        #pragma unroll 8
        for (int e = 0; e < 32; e++) {
            float4 w = *(const float4*)(&Wt[e][vg*4]);
            float4 u = *(const float4*)(&Ut[ec + e][bg*4]);
            acc[0][0] += w.x*u.x; acc[0][1] += w.x*u.y; acc[0][2] += w.x*u.z; acc[0][3] += w.x*u.w;
            acc[1][0] += w.y*u.x; acc[1][1] += w.y*u.y; acc[1][2] += w.y*u.z; acc[1][3] += w.y*u.w;
            acc[2][0] += w.z*u.x; acc[2][1] += w.z*u.y; acc[2][2] += w.z*u.z; acc[2][3] += w.z*u.w;
            acc[3][0] += w.w*u.x; acc[3][1] += w.w*u.y; acc[3][2] += w.w*u.z; acc[3][3] += w.w*u.w;
        }
    }
    // epilogue: v = v0 + 4*vg + i, b = 4*bg + j
    #pragma unroll
    for (int i = 0; i < 4; i++) {
        int v = v0 + vg*4 + i;
        if (v < VV) {
            float bb = bv[v];
            #pragma unroll
            for (int j = 0; j < 4; j++)
                logits[(size_t)(bg*4 + j)*VV + v] = acc[i][j] + bb;
        }
    }
}

// ---------------- vocab softmax partial stats: 8 chunks per batch row ----------------
#define VCHUNK 6250
__global__ __launch_bounds__(256) void vpart_kernel(
    const float* __restrict__ logits, // [B][V]
    float* __restrict__ part)         // [B][8][2] = {max, sumexp}
{
    int blk = blockIdx.x;             // b*8 + c
    int b = blk >> 3, c = blk & 7;
    int t = threadIdx.x;
    const float* row = logits + (size_t)b*VV;
    int start = c*VCHUNK;
    int end   = min(start + VCHUNK, VV);
    __shared__ float red[4];
    int w = t >> 6, lane = t & 63;
    float mx = -INFINITY;
    for (int i = start + t; i < end; i += 256) mx = fmaxf(mx, row[i]);
    #pragma unroll
    for (int off = 32; off; off >>= 1) mx = fmaxf(mx, __shfl_down(mx, off));
    if (lane == 0) red[w] = mx;
    __syncthreads();
    float m = fmaxf(fmaxf(red[0], red[1]), fmaxf(red[2], red[3]));
    float sum = 0.f;
    for (int i = start + t; i < end; i += 256) sum += __expf(row[i] - m);
    #pragma unroll
    for (int off = 32; off; off >>= 1) sum += __shfl_down(sum, off);
    __syncthreads();
    if (lane == 0) red[w] = sum;
    __syncthreads();
    if (t == 0) {
        part[blk*2]   = m;
        part[blk*2+1] = red[0] + red[1] + red[2] + red[3];
    }
}

// ---------------- finalize p_vocab in place (combine partials per element) ----------------
__global__ __launch_bounds__(256) void vfinal_kernel(
    float* __restrict__ logits,       // [B][V], in-place
    const float* __restrict__ part)   // [B][8][2]
{
    int i = blockIdx.x*256 + threadIdx.x;
    if (i >= BB*VV) return;
    int b = i / VV;
    const float* pp = part + b*16;
    float M = -INFINITY;
    #pragma unroll
    for (int c = 0; c < 8; c++) M = fmaxf(M, pp[c*2]);
    float S = 0.f;
    #pragma unroll
    for (int c = 0; c < 8; c++) S += pp[c*2+1] * __expf(pp[c*2] - M);
    logits[i] = __expf(logits[i] - M) * (1.f / S);
}

extern "C" void kernel_launch(void* const* d_in, const int* in_sizes, int n_in,
                              void* d_out, int out_size, void* d_ws, size_t ws_size,
                              hipStream_t stream) {
    const int*   ctx    = (const int*)  d_in[0];
    const float* h_prev = (const float*)d_in[1];
    const int*   y      = (const int*)  d_in[2];
    const float* emb    = (const float*)d_in[3];
    const float* W_ih   = (const float*)d_in[4];
    const float* W_hh   = (const float*)d_in[5];
    const float* b_ih   = (const float*)d_in[6];
    const float* b_hh   = (const float*)d_in[7];
    const float* Wv     = (const float*)d_in[8];
    const float* bv     = (const float*)d_in[9];

    float* out_h    = (float*)d_out;                 // [B][G]
    float* out_pv   = out_h + BB*GG;                 // [B][V]
    float* out_attn = out_pv + (size_t)BB*VV;        // [B][M]

    float* ws     = (float*)d_ws;
    float* q      = ws;                    // 4096
    float* o1     = q + BB*EE;             // 4096
    float* o_part = o1 + BB*EE;            // 32*32*128 = 131072
    float* p      = o_part + 32*BB*EE;     // 65536
    float* attn   = p + BB*MM;             // 65536
    float* part   = attn + BB*MM;          // 512

    gru_kernel<<<BB, 384, 0, stream>>>(emb, y, h_prev, W_ih, W_hh, b_ih, b_hh, out_h, q);

    for (int hop = 0; hop < HOPS; hop++) {
        const float* embA = emb + (size_t)hop*VV*EE;
        const float* embC = emb + (size_t)(hop+1)*VV*EE;
        scores_kernel<<<(BB*MM)/4, 256, 0, stream>>>(embA, ctx, q, p);
        float* attn_dst = (hop == HOPS-1) ? out_attn : attn;
        softmax_m_kernel<<<BB, 256, 0, stream>>>(p, attn_dst);
        oacc_kernel<<<BB*32, 256, 0, stream>>>(embC, ctx, attn_dst, o_part);
        qupd_kernel<<<(BB*EE)/256, 256, 0, stream>>>(o_part, q, o1, hop == 0 ? 1 : 0);
    }

    logits_kernel<<<(VV + 127)/128, 256, 0, stream>>>(out_h, o1, Wv, bv, out_pv);
    vpart_kernel<<<BB*8, 256, 0, stream>>>(out_pv, part);
    vfinal_kernel<<<(BB*VV + 255)/256, 256, 0, stream>>>(out_pv, part);
}